// Round 13
// baseline (201.415 us; speedup 1.0000x reference)
//
#include <hip/hip_runtime.h>

// Problem constants
#define V_N 256
#define T_N 256
#define K_N 36
#define L_N 32
#define D_N 1024
#define MROWS (V_N * K_N)         // 9216
#define NROWS (T_N * L_N)         // 8192
#define BM 256
#define BN 128
#define KSTEPS 16                 // K-tiles of 64
#define NBM (MROWS / BM)          // 36
#define NBN (NROWS / BN)          // 64
#define NWG (NBM * NBN)           // 2304 (divisible by 8)

typedef __attribute__((ext_vector_type(8))) short bf16x8;
typedef __attribute__((ext_vector_type(4))) float f32x4;
typedef __attribute__((ext_vector_type(16))) float f32x16;

#define SB0 __builtin_amdgcn_sched_barrier(0)

__device__ __forceinline__ ushort f2bf(float x) {
  union { float f; unsigned int u; } c; c.f = x;
  unsigned int r = c.u + 0x7FFFu + ((c.u >> 16) & 1u);
  return (ushort)(r >> 16);
}

// ---------------- cvt A: fp32 -> 32x32x16-fragment-tiled bf16 ---------------
// Fragment h = rb*64 + s (rb=rowblock32 0..287, s=kstep16 0..63), 512 ushorts:
// lane l supplies A[rb*32 + (l&31)][s*16 + (l>>5)*8 .. +8] — the 32x32x16
// operand layout verified by R11 (rdA/b2 passing with absmax 8192).
__global__ void cvt_a2(const float* __restrict__ imgs, ushort* __restrict__ a2) {
  const int NH = (MROWS / 32) * 64;         // 18432 fragments
  int gid = blockIdx.x * blockDim.x + threadIdx.x;
  int h = gid >> 6;
  int lane = gid & 63;
  if (h >= NH) return;
  int rb = h >> 6;
  int s  = h & 63;
  int row = rb * 32 + (lane & 31);
  int k   = s * 16 + ((lane >> 5) << 3);
  const float4* src = reinterpret_cast<const float4*>(imgs + (size_t)row * D_N + k);
  float4 f0 = src[0], f1 = src[1];
  union { ushort u[8]; int4 v4; } pk;
  pk.u[0] = f2bf(f0.x); pk.u[1] = f2bf(f0.y); pk.u[2] = f2bf(f0.z); pk.u[3] = f2bf(f0.w);
  pk.u[4] = f2bf(f1.x); pk.u[5] = f2bf(f1.y); pk.u[6] = f2bf(f1.z); pk.u[7] = f2bf(f1.w);
  *reinterpret_cast<int4*>(a2 + (size_t)h * 512 + lane * 8) = pk.v4;
}

// ---------------- cvt B: fp32 -> 32x32x16-fragment-tiled bf16 (R11) ---------
__global__ void cvt_b2(const float* __restrict__ caps, ushort* __restrict__ b2) {
  const int NH = 256 * 64;                  // 16384 fragments
  int gid = blockIdx.x * blockDim.x + threadIdx.x;
  int h = gid >> 6;
  int lane = gid & 63;
  if (h >= NH) return;
  int c = h >> 6;
  int s = h & 63;
  int col = c * 32 + (lane & 31);
  int k   = s * 16 + ((lane >> 5) << 3);
  const float4* src = reinterpret_cast<const float4*>(caps + (size_t)col * D_N + k);
  float4 f0 = src[0], f1 = src[1];
  union { ushort u[8]; int4 v4; } pk;
  pk.u[0] = f2bf(f0.x); pk.u[1] = f2bf(f0.y); pk.u[2] = f2bf(f0.z); pk.u[3] = f2bf(f0.w);
  pk.u[4] = f2bf(f1.x); pk.u[5] = f2bf(f1.y); pk.u[6] = f2bf(f1.z); pk.u[7] = f2bf(f1.w);
  *reinterpret_cast<int4*>(b2 + (size_t)h * 512 + lane * 8) = pk.v4;
}

// ---------------- barrier-free all-register GEMM + square + block-sum -------
// S = A*B^T (bf16, fp32 acc); out[v,t] += sum of squares, v=arow/36, t=bcol/32.
//
// R12: NO LDS, NO barriers. Each wave owns a 128x64 output and independently
// streams its fragments straight from the pre-tiled a2/b2 (coalesced 16B/lane
// dwordx4, L2-resident via bn-band XCD map; L1 dedups the 2x intra-block
// operand sharing). Register double-buffer at half-K-tile granularity
// (sets 0/1, statically named — no runtime indexing): per half issue 12
// loads for the NEXT half, per-wave counted vmcnt(12) gate before consuming
// the current half (vmcnt(0) only at the very last half). Every tile
// boundary that R2-R11 paid (~300-900 cyc barrier/drain latency, the
// measured serial-sum limiter) is gone; waves on a SIMD desync freely.
__global__ __launch_bounds__(256, 2) void gemm4(
    const ushort* __restrict__ a2, const ushort* __restrict__ b2,
    float* __restrict__ out) {
  int orig = (int)blockIdx.x;
  int xcd = orig & 7;
  int idx = orig >> 3;                  // 0..287
  const int bn = xcd * 8 + (idx & 7);   // 8-wide bn band per XCD (B 2MB L2-hot)
  const int bm = idx >> 3;              // 0..35, slow sweep
  const int row0 = bm * BM;
  const int col0 = bn * BN;

  const int tid  = (int)threadIdx.x;
  const int lane = tid & 63;
  const int wid  = tid >> 6;
  const int wr   = wid >> 1;     // 0..1 -> 128-row slab
  const int wc   = wid & 1;      // 0..1 -> 64-col slab

  // per-wave fragment stream bases (frag = 512 ushorts, lane-contiguous)
  const ushort* aw = a2 + ((size_t)(bm * 8 + wr * 4) * 64) * 512 + lane * 8;
  const ushort* bw = b2 + ((size_t)(bn * 4 + wc * 2) * 64) * 512 + lane * 8;

  // A frag (mt 0..3, s 0..63): aw + (mt*64 + s)*512
  // B frag (nt 0..1, s 0..63): bw + (nt*64 + s)*512

  f32x16 acc[4][2];
#pragma unroll
  for (int mt = 0; mt < 4; ++mt)
#pragma unroll
    for (int nt = 0; nt < 2; ++nt)
#pragma unroll
      for (int j = 0; j < 16; ++j) acc[mt][nt][j] = 0.f;

  bf16x8 A0[8], B0[4], A1[8], B1[4];   // set = {4mt x 2ks A, 2nt x 2ks B}

  // issue one half-tile's 12 loads into a named set. p=0 -> ks {0,1}, p=1 -> {2,3}
#define ISSUE(Aset, Bset, t, p)                                              \
  {                                                                          \
    int s0 = (t) * 4 + (p) * 2;                                              \
    _Pragma("unroll")                                                        \
    for (int mt = 0; mt < 4; ++mt) {                                         \
      Aset[mt * 2]     = *reinterpret_cast<const bf16x8*>(aw + ((size_t)mt * 64 + s0) * 512);     \
      Aset[mt * 2 + 1] = *reinterpret_cast<const bf16x8*>(aw + ((size_t)mt * 64 + s0 + 1) * 512); \
    }                                                                        \
    _Pragma("unroll")                                                        \
    for (int nt = 0; nt < 2; ++nt) {                                         \
      Bset[nt * 2]     = *reinterpret_cast<const bf16x8*>(bw + ((size_t)nt * 64 + s0) * 512);     \
      Bset[nt * 2 + 1] = *reinterpret_cast<const bf16x8*>(bw + ((size_t)nt * 64 + s0 + 1) * 512); \
    }                                                                        \
  }

#define MFMA16(Aset, Bset)                                                   \
  {                                                                          \
    _Pragma("unroll")                                                        \
    for (int ksl = 0; ksl < 2; ++ksl)                                        \
      _Pragma("unroll")                                                      \
      for (int mt = 0; mt < 4; ++mt)                                         \
        _Pragma("unroll")                                                    \
        for (int nt = 0; nt < 2; ++nt)                                       \
          acc[mt][nt] = __builtin_amdgcn_mfma_f32_32x32x16_bf16(             \
              Aset[mt * 2 + ksl], Bset[nt * 2 + ksl], acc[mt][nt], 0, 0, 0); \
  }

  // ---- prologue: both halves of tile 0 in flight (24 loads)
  ISSUE(A0, B0, 0, 0); SB0;
  ISSUE(A1, B1, 0, 1); SB0;

  // ---- main loop: per-wave pipeline, no barriers
  for (int t = 0; t < KSTEPS; ++t) {
    asm volatile("s_waitcnt vmcnt(12)" ::: "memory");   // even half landed
    SB0;
    MFMA16(A0, B0);
    SB0;
    if (t < KSTEPS - 1) { ISSUE(A0, B0, t + 1, 0); }    // refill even set
    SB0;
    if (t < KSTEPS - 1) { asm volatile("s_waitcnt vmcnt(12)" ::: "memory"); }
    else                { asm volatile("s_waitcnt vmcnt(0)"  ::: "memory"); }
    SB0;
    MFMA16(A1, B1);
    SB0;
    if (t < KSTEPS - 1) { ISSUE(A1, B1, t + 1, 1); }    // refill odd set
    SB0;
  }

  // ---- epilogue: squared block-sums.
  // 32x32 C/D: col = lane&31, row = (reg&3) + 8*(reg>>2) + 4*(lane>>5).
#pragma unroll
  for (int mt = 0; mt < 4; ++mt) {
    int gbase = row0 + wr * 128 + mt * 32;
    int v0 = gbase / K_N;
    int b = (v0 + 1) * K_N;
#pragma unroll
    for (int nt = 0; nt < 2; ++nt) {
      f32x16 a = acc[mt][nt];
      float s0 = 0.f, s1 = 0.f;
#pragma unroll
      for (int j = 0; j < 16; ++j) {
        int row = (j & 3) + 8 * (j >> 2) + 4 * (lane >> 5);
        float x = a[j];
        float x2 = x * x;
        if (gbase + row < b) s0 += x2; else s1 += x2;
      }
#pragma unroll
      for (int off = 32; off > 0; off >>= 1) {
        s0 += __shfl_xor(s0, off, 64);
        s1 += __shfl_xor(s1, off, 64);
      }
      if (lane == 0) {
        int tcol = (col0 + wc * 64 + nt * 32) >> 5;
        atomicAdd(out + v0 * T_N + tcol, s0);
        if (b < gbase + 32) atomicAdd(out + (v0 + 1) * T_N + tcol, s1);
      }
    }
  }
#undef ISSUE
#undef MFMA16
}

// ---------------- fallback (no workspace): R1's 128x128 reg-staged kernel ---
__global__ __launch_bounds__(256) void gemm_fb(
    const float* __restrict__ imgs, const float* __restrict__ caps,
    float* __restrict__ out) {
  __shared__ ushort lds[128 * 64 + 128 * 64];
  ushort* ldsA = lds;
  ushort* ldsB = lds + 128 * 64;
  const int NBMf = MROWS / 128, NBNf = NROWS / 128;
  int orig = (int)blockIdx.x;
  int xcd = orig & 7;
  int idx = orig >> 3;
  int bn = xcd * (NBNf / 8) + (idx % (NBNf / 8));
  int bm = idx / (NBNf / 8);
  const int row0 = bm * 128, col0 = bn * 128;
  const int tid = (int)threadIdx.x, lane = tid & 63, wid = tid >> 6;
  const int wr = wid >> 1, wc = wid & 1;
  f32x4 acc[4][4];
#pragma unroll
  for (int i = 0; i < 4; ++i)
#pragma unroll
    for (int j = 0; j < 4; ++j) acc[i][j] = (f32x4){0.f, 0.f, 0.f, 0.f};
  for (int kt = 0; kt < KSTEPS; ++kt) {
#pragma unroll
    for (int it = 0; it < 4; ++it) {
      int q = it * 256 + tid;
      int r = q >> 3;
      int sw = ((q & 7) << 4) ^ ((r & 7) << 4);
      const float4* src = reinterpret_cast<const float4*>(
          imgs + (size_t)(row0 + r) * D_N + kt * 64 + (sw >> 1));
      float4 f0 = src[0], f1 = src[1];
      union { ushort u[8]; int4 v4; } pk;
      pk.u[0] = f2bf(f0.x); pk.u[1] = f2bf(f0.y); pk.u[2] = f2bf(f0.z); pk.u[3] = f2bf(f0.w);
      pk.u[4] = f2bf(f1.x); pk.u[5] = f2bf(f1.y); pk.u[6] = f2bf(f1.z); pk.u[7] = f2bf(f1.w);
      *reinterpret_cast<int4*>(ldsA + q * 8) = pk.v4;
    }
#pragma unroll
    for (int it = 0; it < 4; ++it) {
      int q = it * 256 + tid;
      int r = q >> 3;
      int sw = ((q & 7) << 4) ^ ((r & 7) << 4);
      const float4* src = reinterpret_cast<const float4*>(
          caps + (size_t)(col0 + r) * D_N + kt * 64 + (sw >> 1));
      float4 f0 = src[0], f1 = src[1];
      union { ushort u[8]; int4 v4; } pk;
      pk.u[0] = f2bf(f0.x); pk.u[1] = f2bf(f0.y); pk.u[2] = f2bf(f0.z); pk.u[3] = f2bf(f0.w);
      pk.u[4] = f2bf(f1.x); pk.u[5] = f2bf(f1.y); pk.u[6] = f2bf(f1.z); pk.u[7] = f2bf(f1.w);
      *reinterpret_cast<int4*>(ldsB + q * 8) = pk.v4;
    }
    __syncthreads();
#pragma unroll
    for (int ks = 0; ks < 2; ++ks) {
      bf16x8 afr[4], bfr[4];
#pragma unroll
      for (int i = 0; i < 4; ++i) {
        int r = wr * 64 + i * 16 + (lane & 15);
        int sw = (ks * 64 + (((lane >> 4) << 4))) ^ ((r & 7) << 4);
        afr[i] = *reinterpret_cast<const bf16x8*>(ldsA + r * 64 + (sw >> 1));
      }
#pragma unroll
      for (int j = 0; j < 4; ++j) {
        int r = wc * 64 + j * 16 + (lane & 15);
        int sw = (ks * 64 + (((lane >> 4) << 4))) ^ ((r & 7) << 4);
        bfr[j] = *reinterpret_cast<const bf16x8*>(ldsB + r * 64 + (sw >> 1));
      }
#pragma unroll
      for (int i = 0; i < 4; ++i)
#pragma unroll
        for (int j = 0; j < 4; ++j)
          acc[i][j] = __builtin_amdgcn_mfma_f32_16x16x32_bf16(afr[i], bfr[j], acc[i][j], 0, 0, 0);
    }
    __syncthreads();
  }
#pragma unroll
  for (int i = 0; i < 4; ++i) {
#pragma unroll
    for (int j = 0; j < 4; ++j) {
      f32x4 a4 = acc[i][j];
      int grow = row0 + wr * 64 + i * 16;
      int gcol = col0 + wc * 64 + j * 16;
      int t = gcol >> 5;
      int v0 = grow / K_N;
      int b = (v0 + 1) * K_N;
      int rbase = grow + ((lane >> 4) << 2);
      float s0 = 0.f, s1 = 0.f;
#pragma unroll
      for (int rg = 0; rg < 4; ++rg) {
        float x = a4[rg];
        float x2 = x * x;
        if (rbase + rg < b) s0 += x2; else s1 += x2;
      }
#pragma unroll
      for (int off = 32; off > 0; off >>= 1) {
        s0 += __shfl_xor(s0, off, 64);
        s1 += __shfl_xor(s1, off, 64);
      }
      if (lane == 0) {
        atomicAdd(out + v0 * T_N + t, s0);
        if (b < grow + 16) atomicAdd(out + (v0 + 1) * T_N + t, s1);
      }
    }
  }
}

extern "C" void kernel_launch(void* const* d_in, const int* in_sizes, int n_in,
                              void* d_out, int out_size, void* d_ws, size_t ws_size,
                              hipStream_t stream) {
  const float* imgs = (const float*)d_in[0];
  const float* caps = (const float*)d_in[1];
  float* out = (float*)d_out;

  hipMemsetAsync(d_out, 0, (size_t)V_N * T_N * sizeof(float), stream);

  const size_t need = (size_t)(MROWS + NROWS) * D_N * sizeof(ushort);  // ~36 MB

  if (ws_size >= need) {
    ushort* a2 = (ushort*)d_ws;
    ushort* b2 = a2 + (size_t)MROWS * D_N;
    cvt_a2<<<4608, 256, 0, stream>>>(imgs, a2);
    cvt_b2<<<4096, 256, 0, stream>>>(caps, b2);
    gemm4<<<NWG, 256, 0, stream>>>(a2, b2, out);
  } else {
    const int nwg = (MROWS / 128) * (NROWS / 128);
    gemm_fb<<<nwg, 256, 0, stream>>>(imgs, caps, out);
  }
}

// Round 14
// 179.286 us; speedup vs baseline: 1.1234x; 1.1234x over previous
//
#include <hip/hip_runtime.h>

// Problem constants
#define V_N 256
#define T_N 256
#define K_N 36
#define L_N 32
#define D_N 1024
#define MROWS (V_N * K_N)         // 9216
#define NROWS (T_N * L_N)         // 8192
#define BM 256
#define BN 256
#define BK 64                     // bf16 elems per K-tile
#define KSTEPS (D_N / BK)         // 16
#define NBM (MROWS / BM)          // 36
#define NBN (NROWS / BN)          // 32
#define NWG (NBM * NBN)           // 1152 (divisible by 8)

typedef __attribute__((ext_vector_type(8))) short bf16x8;
typedef __attribute__((ext_vector_type(4))) float f32x4;

#define BAR __builtin_amdgcn_s_barrier()
#define LGK0 asm volatile("s_waitcnt lgkmcnt(0)" ::: "memory")

__device__ __forceinline__ ushort f2bf(float x) {
  union { float f; unsigned int u; } c; c.f = x;
  unsigned int r = c.u + 0x7FFFu + ((c.u >> 16) & 1u);
  return (ushort)(r >> 16);
}

// ---------------- conversion kernel: fp32 -> bf16 workspace (flat cast) -----
__global__ void cvt_cast(const float* __restrict__ imgs, const float* __restrict__ caps,
                         ushort* __restrict__ aws, ushort* __restrict__ bws) {
  const int AQ = MROWS * (D_N / 4);
  const int BQ = NROWS * (D_N / 4);
  const int total = AQ + BQ;
  for (int q = blockIdx.x * blockDim.x + threadIdx.x; q < total;
       q += gridDim.x * blockDim.x) {
    float4 f;
    ushort4* dst;
    if (q < AQ) {
      f = reinterpret_cast<const float4*>(imgs)[q];
      dst = reinterpret_cast<ushort4*>(aws) + q;
    } else {
      f = reinterpret_cast<const float4*>(caps)[q - AQ];
      dst = reinterpret_cast<ushort4*>(bws) + (q - AQ);
    }
    ushort4 u; u.x = f2bf(f.x); u.y = f2bf(f.y); u.z = f2bf(f.z); u.w = f2bf(f.w);
    *dst = u;
  }
}

// ---------------- 256x256 8-phase GEMM + square + block-sum (NO SB0) --------
// S = A*B^T (bf16, fp32 acc); out[v,t] += sum of squares, v=arow/36, t=bcol/32.
//
// R13 = R5's proven body with every sched_barrier(0) REMOVED (m141: SB0
// order-pinning defeats compiler scheduling, -42% there). Correctness fences:
// the asm waitcnts carry "memory" clobbers, which order all compiler-visible
// LDS/global accesses across them; MFMA consumes loaded VALUES (data deps),
// so it can never execute before its operands regardless of scheduling.
// Phase structure per K-tile (m201 template): 4 phases, each {ds-reads;
// stage 1 16KB unit; barrier; lgkmcnt(0); 16 MFMA with setprio; barrier};
// counted vmcnt gates at p1-end (10) and p3-end (8), never 0 in steady state.
// Stage stream (race math verified in R4): Am47(t+1)@p0, Am03(t+2)@p1,
// B1(t+2)@p2, B2(t+2)@p3. Tail gates 8/2 then 0/0.
// XCD locality (R5): each XCD owns a 4-wide bn band (B L2-resident);
// bm sweeps slowly. FETCH measured 114 MB.
__global__ __launch_bounds__(512, 2) void gemm2(
    const ushort* __restrict__ aws, const ushort* __restrict__ bws,
    float* __restrict__ out) {
  __shared__ ushort lds[2 * 2 * BM * BK];   // 128 KiB

  int orig = (int)blockIdx.x;
  int xcd = orig & 7;
  int idx = orig >> 3;                 // 0..143
  const int bn = xcd * 4 + (idx & 3);
  const int bm = idx >> 2;             // slow sweep
  const int row0 = bm * BM;
  const int col0 = bn * BN;

  const int tid  = (int)threadIdx.x;
  const int lane = tid & 63;
  const int wid  = tid >> 6;
  const int wr   = wid >> 2;     // 0..1  -> 128-row A slab
  const int wc   = wid & 3;      // 0..3  -> 64-row B slab

  const int kb  = (lane >> 4) << 4;   // byte offset within 64B k-slice

  // stage one 16KB unit (2 gload_lds/thread). kinds:
  // 0=Am03 rows{0-63,128-191}, 1=Am47 rows{64-127,192-255},
  // 2=B1 rows{0-127}, 3=B2 rows{128-255}
  auto stage_unit = [&](int kt, int kind) {
    const int rb0 = (kind == 0) ? 0 : (kind == 1) ? 64 : (kind == 2) ? 0 : 128;
    const int rb1 = (kind == 0) ? 128 : (kind == 1) ? 192 : (kind == 2) ? 64 : 192;
    ushort* base = lds + (kt & 1) * (2 * BM * BK) + ((kind >= 2) ? BM * BK : 0);
    const ushort* g = (kind >= 2) ? bws : aws;
    const int g0 = (kind >= 2) ? col0 : row0;
#pragma unroll
    for (int j = 0; j < 2; ++j) {
      int r = (j ? rb1 : rb0) + (tid >> 3);
      int sw = ((tid & 7) << 4) ^ ((r & 7) << 4);
      const ushort* src = g + (size_t)(g0 + r) * D_N + kt * BK + (sw >> 1);
      __builtin_amdgcn_global_load_lds(
          (const __attribute__((address_space(1))) void*)src,
          (__attribute__((address_space(3))) void*)(base + r * BK + (tid & 7) * 8),
          16, 0, 0);
    }
  };

  auto rdA = [&](const ushort* bufA, int m, int ks) -> bf16x8 {
    int r = wr * 128 + m * 16 + (lane & 15);
    int sw = (ks * 64 + kb) ^ ((r & 7) << 4);
    return *reinterpret_cast<const bf16x8*>(bufA + r * BK + (sw >> 1));
  };
  auto rdB = [&](const ushort* bufB, int n, int ks) -> bf16x8 {
    int r = wc * 64 + n * 16 + (lane & 15);
    int sw = (ks * 64 + kb) ^ ((r & 7) << 4);
    return *reinterpret_cast<const bf16x8*>(bufB + r * BK + (sw >> 1));
  };

  f32x4 acc[8][4];
#pragma unroll
  for (int m = 0; m < 8; ++m)
#pragma unroll
    for (int n = 0; n < 4; ++n) acc[m][n] = (f32x4){0.f, 0.f, 0.f, 0.f};

  // ---- prologue: t0 fully + t1's {Am03,B1,B2}; gate so t0 landed
  stage_unit(0, 0); stage_unit(0, 2); stage_unit(0, 3); stage_unit(0, 1);
  stage_unit(1, 0); stage_unit(1, 2); stage_unit(1, 3);
  asm volatile("s_waitcnt vmcnt(6)" ::: "memory");
  BAR;

  // ---- main loop
  for (int t = 0; t < KSTEPS; ++t) {
    const ushort* bufA = lds + (t & 1) * (2 * BM * BK);
    const ushort* bufB = bufA + BM * BK;
    bf16x8 aA[8], b01[4], b23[4];

    // ======== p0: reads A(m0-3,2ks)+B(n0-1,2ks); stage Am47(t+1)
#pragma unroll
    for (int m = 0; m < 4; ++m) { aA[m] = rdA(bufA, m, 0); aA[4 + m] = rdA(bufA, m, 1); }
#pragma unroll
    for (int n = 0; n < 2; ++n) { b01[n] = rdB(bufB, n, 0); b01[2 + n] = rdB(bufB, n, 1); }
    if (t <= KSTEPS - 2) stage_unit(t + 1, 1);
    BAR; LGK0;
    __builtin_amdgcn_s_setprio(1);
#pragma unroll
    for (int m = 0; m < 4; ++m)
#pragma unroll
      for (int n = 0; n < 2; ++n)
        acc[m][n] = __builtin_amdgcn_mfma_f32_16x16x32_bf16(aA[m], b01[n], acc[m][n], 0, 0, 0);
#pragma unroll
    for (int m = 0; m < 4; ++m)
#pragma unroll
      for (int n = 0; n < 2; ++n)
        acc[m][n] = __builtin_amdgcn_mfma_f32_16x16x32_bf16(aA[4 + m], b01[2 + n], acc[m][n], 0, 0, 0);
    __builtin_amdgcn_s_setprio(0);
    BAR;

    // ======== p1: reads B(n2-3,2ks); stage Am03(t+2); gate vmcnt
#pragma unroll
    for (int n = 0; n < 2; ++n) { b23[n] = rdB(bufB, 2 + n, 0); b23[2 + n] = rdB(bufB, 2 + n, 1); }
    if (t <= KSTEPS - 3) stage_unit(t + 2, 0);
    BAR; LGK0;
    __builtin_amdgcn_s_setprio(1);
#pragma unroll
    for (int m = 0; m < 4; ++m)
#pragma unroll
      for (int n = 0; n < 2; ++n)
        acc[m][2 + n] = __builtin_amdgcn_mfma_f32_16x16x32_bf16(aA[m], b23[n], acc[m][2 + n], 0, 0, 0);
#pragma unroll
    for (int m = 0; m < 4; ++m)
#pragma unroll
      for (int n = 0; n < 2; ++n)
        acc[m][2 + n] = __builtin_amdgcn_mfma_f32_16x16x32_bf16(aA[4 + m], b23[2 + n], acc[m][2 + n], 0, 0, 0);
    __builtin_amdgcn_s_setprio(0);
    if (t <= KSTEPS - 3)      { asm volatile("s_waitcnt vmcnt(10)" ::: "memory"); }
    else if (t == KSTEPS - 2) { asm volatile("s_waitcnt vmcnt(8)"  ::: "memory"); }
    else                      { asm volatile("s_waitcnt vmcnt(0)"  ::: "memory"); }
    BAR;

    // ======== p2: reads A(m4-7,2ks); stage B1(t+2)
#pragma unroll
    for (int m = 0; m < 4; ++m) { aA[m] = rdA(bufA, 4 + m, 0); aA[4 + m] = rdA(bufA, 4 + m, 1); }
    if (t <= KSTEPS - 3) stage_unit(t + 2, 2);
    BAR; LGK0;
    __builtin_amdgcn_s_setprio(1);
#pragma unroll
    for (int m = 0; m < 4; ++m)
#pragma unroll
      for (int n = 0; n < 2; ++n)
        acc[4 + m][n] = __builtin_amdgcn_mfma_f32_16x16x32_bf16(aA[m], b01[n], acc[4 + m][n], 0, 0, 0);
#pragma unroll
    for (int m = 0; m < 4; ++m)
#pragma unroll
      for (int n = 0; n < 2; ++n)
        acc[4 + m][n] = __builtin_amdgcn_mfma_f32_16x16x32_bf16(aA[4 + m], b01[2 + n], acc[4 + m][n], 0, 0, 0);
    __builtin_amdgcn_s_setprio(0);
    BAR;

    // ======== p3: no reads; stage B2(t+2); gate vmcnt
    if (t <= KSTEPS - 3) stage_unit(t + 2, 3);
    BAR;
    __builtin_amdgcn_s_setprio(1);
#pragma unroll
    for (int m = 0; m < 4; ++m)
#pragma unroll
      for (int n = 0; n < 2; ++n)
        acc[4 + m][2 + n] = __builtin_amdgcn_mfma_f32_16x16x32_bf16(aA[m], b23[n], acc[4 + m][2 + n], 0, 0, 0);
#pragma unroll
    for (int m = 0; m < 4; ++m)
#pragma unroll
      for (int n = 0; n < 2; ++n)
        acc[4 + m][2 + n] = __builtin_amdgcn_mfma_f32_16x16x32_bf16(aA[4 + m], b23[2 + n], acc[4 + m][2 + n], 0, 0, 0);
    __builtin_amdgcn_s_setprio(0);
    if (t <= KSTEPS - 3)      { asm volatile("s_waitcnt vmcnt(8)" ::: "memory"); }
    else if (t == KSTEPS - 2) { asm volatile("s_waitcnt vmcnt(2)" ::: "memory"); }
    else                      { asm volatile("s_waitcnt vmcnt(0)" ::: "memory"); }
    BAR;
  }

  // ---- epilogue: squared block-sums. C/D: col=lane&15, row=(lane>>4)*4+reg.
#pragma unroll
  for (int m = 0; m < 8; ++m) {
    int grow = row0 + wr * 128 + m * 16;
    int v0 = grow / K_N;
    int b = (v0 + 1) * K_N;
    int rb = grow + ((lane >> 4) << 2);
#pragma unroll
    for (int np = 0; np < 2; ++np) {
      float s0 = 0.f, s1 = 0.f;
#pragma unroll
      for (int nn = 0; nn < 2; ++nn) {
        f32x4 a4 = acc[m][np * 2 + nn];
#pragma unroll
        for (int rg = 0; rg < 4; ++rg) {
          float x = a4[rg];
          float x2 = x * x;
          if (rb + rg < b) s0 += x2; else s1 += x2;
        }
      }
#pragma unroll
      for (int off = 32; off > 0; off >>= 1) {
        s0 += __shfl_xor(s0, off, 64);
        s1 += __shfl_xor(s1, off, 64);
      }
      if (lane == 0) {
        int tcol = (col0 + wc * 64 + np * 32) >> 5;
        atomicAdd(out + v0 * T_N + tcol, s0);
        if (grow + 16 > b) atomicAdd(out + (v0 + 1) * T_N + tcol, s1);
      }
    }
  }
}

// ---------------- fallback (no workspace): R1's 128x128 reg-staged kernel ---
__global__ __launch_bounds__(256) void gemm_fb(
    const float* __restrict__ imgs, const float* __restrict__ caps,
    float* __restrict__ out) {
  __shared__ ushort lds[128 * 64 + 128 * 64];
  ushort* ldsA = lds;
  ushort* ldsB = lds + 128 * 64;
  const int NBMf = MROWS / 128, NBNf = NROWS / 128;
  int orig = (int)blockIdx.x;
  int xcd = orig & 7;
  int idx = orig >> 3;
  int bn = xcd * (NBNf / 8) + (idx % (NBNf / 8));
  int bm = idx / (NBNf / 8);
  const int row0 = bm * 128, col0 = bn * 128;
  const int tid = (int)threadIdx.x, lane = tid & 63, wid = tid >> 6;
  const int wr = wid >> 1, wc = wid & 1;
  f32x4 acc[4][4];
#pragma unroll
  for (int i = 0; i < 4; ++i)
#pragma unroll
    for (int j = 0; j < 4; ++j) acc[i][j] = (f32x4){0.f, 0.f, 0.f, 0.f};
  for (int kt = 0; kt < KSTEPS; ++kt) {
#pragma unroll
    for (int it = 0; it < 4; ++it) {
      int q = it * 256 + tid;
      int r = q >> 3;
      int sw = ((q & 7) << 4) ^ ((r & 7) << 4);
      const float4* src = reinterpret_cast<const float4*>(
          imgs + (size_t)(row0 + r) * D_N + kt * 64 + (sw >> 1));
      float4 f0 = src[0], f1 = src[1];
      union { ushort u[8]; int4 v4; } pk;
      pk.u[0] = f2bf(f0.x); pk.u[1] = f2bf(f0.y); pk.u[2] = f2bf(f0.z); pk.u[3] = f2bf(f0.w);
      pk.u[4] = f2bf(f1.x); pk.u[5] = f2bf(f1.y); pk.u[6] = f2bf(f1.z); pk.u[7] = f2bf(f1.w);
      *reinterpret_cast<int4*>(ldsA + q * 8) = pk.v4;
    }
#pragma unroll
    for (int it = 0; it < 4; ++it) {
      int q = it * 256 + tid;
      int r = q >> 3;
      int sw = ((q & 7) << 4) ^ ((r & 7) << 4);
      const float4* src = reinterpret_cast<const float4*>(
          caps + (size_t)(col0 + r) * D_N + kt * 64 + (sw >> 1));
      float4 f0 = src[0], f1 = src[1];
      union { ushort u[8]; int4 v4; } pk;
      pk.u[0] = f2bf(f0.x); pk.u[1] = f2bf(f0.y); pk.u[2] = f2bf(f0.z); pk.u[3] = f2bf(f0.w);
      pk.u[4] = f2bf(f1.x); pk.u[5] = f2bf(f1.y); pk.u[6] = f2bf(f1.z); pk.u[7] = f2bf(f1.w);
      *reinterpret_cast<int4*>(ldsB + q * 8) = pk.v4;
    }
    __syncthreads();
#pragma unroll
    for (int ks = 0; ks < 2; ++ks) {
      bf16x8 afr[4], bfr[4];
#pragma unroll
      for (int i = 0; i < 4; ++i) {
        int r = wr * 64 + i * 16 + (lane & 15);
        int sw = (ks * 64 + (((lane >> 4) << 4))) ^ ((r & 7) << 4);
        afr[i] = *reinterpret_cast<const bf16x8*>(ldsA + r * 64 + (sw >> 1));
      }
#pragma unroll
      for (int j = 0; j < 4; ++j) {
        int r = wc * 64 + j * 16 + (lane & 15);
        int sw = (ks * 64 + (((lane >> 4) << 4))) ^ ((r & 7) << 4);
        bfr[j] = *reinterpret_cast<const bf16x8*>(ldsB + r * 64 + (sw >> 1));
      }
#pragma unroll
      for (int i = 0; i < 4; ++i)
#pragma unroll
        for (int j = 0; j < 4; ++j)
          acc[i][j] = __builtin_amdgcn_mfma_f32_16x16x32_bf16(afr[i], bfr[j], acc[i][j], 0, 0, 0);
    }
    __syncthreads();
  }
#pragma unroll
  for (int i = 0; i < 4; ++i) {
#pragma unroll
    for (int j = 0; j < 4; ++j) {
      f32x4 a4 = acc[i][j];
      int grow = row0 + wr * 64 + i * 16;
      int gcol = col0 + wc * 64 + j * 16;
      int t = gcol >> 5;
      int v0 = grow / K_N;
      int b = (v0 + 1) * K_N;
      int rbase = grow + ((lane >> 4) << 2);
      float s0 = 0.f, s1 = 0.f;
#pragma unroll
      for (int rg = 0; rg < 4; ++rg) {
        float x = a4[rg];
        float x2 = x * x;
        if (rbase + rg < b) s0 += x2; else s1 += x2;
      }
#pragma unroll
      for (int off = 32; off > 0; off >>= 1) {
        s0 += __shfl_xor(s0, off, 64);
        s1 += __shfl_xor(s1, off, 64);
      }
      if (lane == 0) {
        atomicAdd(out + v0 * T_N + t, s0);
        if (b < grow + 16) atomicAdd(out + (v0 + 1) * T_N + t, s1);
      }
    }
  }
}

extern "C" void kernel_launch(void* const* d_in, const int* in_sizes, int n_in,
                              void* d_out, int out_size, void* d_ws, size_t ws_size,
                              hipStream_t stream) {
  const float* imgs = (const float*)d_in[0];
  const float* caps = (const float*)d_in[1];
  float* out = (float*)d_out;

  hipMemsetAsync(d_out, 0, (size_t)V_N * T_N * sizeof(float), stream);

  const size_t need = (size_t)(MROWS + NROWS) * D_N * sizeof(ushort);  // ~36 MB

  if (ws_size >= need) {
    ushort* aws = (ushort*)d_ws;
    ushort* bws = aws + (size_t)MROWS * D_N;
    cvt_cast<<<2048, 256, 0, stream>>>(imgs, caps, aws, bws);
    gemm2<<<NWG, 512, 0, stream>>>(aws, bws, out);
  } else {
    const int nwg = (MROWS / 128) * (NROWS / 128);
    gemm_fb<<<nwg, 256, 0, stream>>>(imgs, caps, out);
  }
}